// Round 3
// baseline (154.421 us; speedup 1.0000x reference)
//
#include <hip/hip_runtime.h>
#include <hip/hip_fp16.h>

// UnbalancedOT Sinkhorn, B=4 H=128 W=512 C=64, EPS=1, TAU=0.95, 10 iters.
// E = exp(-C) stored fp16 in LDS (72 KiB -> 2 blocks/CU, 16 waves/CU).
// All consumers use the same rounded E => exact algorithm on C' = -log(E_h),
// |C'-C| <= 4.9e-4 -> output error ~1e-5 < 3.9e-5 threshold.
// ONE barrier per iteration: u passed intra-wave via shfl (each wave's g-rows
// are its own lanes), v computed redundantly per-wave into private LDS slot,
// block-wide sminF reduction deferred one iteration via unnormalized u
// (u = exp(nf2), shift = XI*sminF2 folded into appg next iter).
// ps/red double-buffered on iteration parity so the single barrier is race-free.

#define WD_ 512
#define CC_ 64
#define NITER_ 10
#define LPH 72   // fp16 row stride in halves (144 B = 9*16: b128-aligned rows,
                 // 36 words/row -> 4-bank rotation, balanced b64 access)

__global__ __launch_bounds__(512, 4)
void uot_sinkhorn_kernel(const float* __restrict__ C, float* __restrict__ out) {
    constexpr float TAU   = 0.95f;
    constexpr float KAPPA = 0.025f;           // (1-TAU)/2
    constexpr float XI    = 0.05f / 1.95f;    // (1-TAU)/(1+TAU)
    constexpr float RHO   = 19.0f;            // EPS*TAU/(1-TAU)
    constexpr float INV_RHO = 1.0f / 19.0f;
    const float log_a = -6.2383246250395075f; // -log(512)
    const float log_b = -4.1588830833596715f; // -log(64)

    __shared__ __align__(16) unsigned short Es[WD_ * LPH]; // 73728 B, fp16 E
    __shared__ __align__(16) float vsb[8 * CC_];           // per-wave v slots
    __shared__ __align__(16) float ps[2][WD_];             // dbuf col partials
    __shared__ __align__(16) float red[2][8];              // dbuf sminF partials

    const int tid  = threadIdx.x;
    const int lane = tid & 63;
    const int wv   = tid >> 6;
    const int r    = lane >> 4;     // 0..3 row-subset
    const int cg   = lane & 15;     // 0..15 col-group of 4
    const int w0   = wv * 64;

    const size_t base = (size_t)blockIdx.x * (WD_ * CC_);
    const float4* Cg4   = reinterpret_cast<const float4*>(C + base);
    float4*       outg4 = reinterpret_cast<float4*>(out + base);

    // ---- stage: coalesced loads of C, E=exp(-C) -> fp16 LDS ----
    #pragma unroll
    for (int i = 0; i < 16; ++i) {
        int fi = i * 512 + tid;
        float4 v = Cg4[fi];
        int w  = fi >> 4;
        int c0 = (fi & 15) << 2;
        __half2 h0 = __floats2half2_rn(__expf(-v.x), __expf(-v.y));
        __half2 h1 = __floats2half2_rn(__expf(-v.z), __expf(-v.w));
        uint2 pk;
        *reinterpret_cast<__half2*>(&pk.x) = h0;
        *reinterpret_cast<__half2*>(&pk.y) = h1;
        *reinterpret_cast<uint2*>(&Es[w * LPH + c0]) = pk;
    }
    __syncthreads();

    // ---- own-row fp32 register copy (f-phase reads no LDS for E) ----
    float4 ER[16];
    #pragma unroll
    for (int k = 0; k < 16; ++k) {
        uint2 raw = *reinterpret_cast<const uint2*>(&Es[tid * LPH + 4 * k]);
        float2 a = __half22float2(*reinterpret_cast<__half2*>(&raw.x));
        float2 b = __half22float2(*reinterpret_cast<__half2*>(&raw.y));
        ER[k] = make_float4(a.x, a.y, b.x, b.y);
    }

    // ---- init f: fv = -(log_b + log sum_c E[row,:]) ; u = exp(fv) ----
    float u_own;
    {
        float s0 = 0.f, s1 = 0.f, s2 = 0.f, s3 = 0.f;
        #pragma unroll
        for (int k = 0; k < 16; ++k) {
            s0 += ER[k].x; s1 += ER[k].y; s2 += ER[k].z; s3 += ER[k].w;
        }
        float fv = -(log_b + __logf((s0 + s1) + (s2 + s3)));
        u_own = __expf(fv);
        float x = __expf(-fv * INV_RHO);
        #pragma unroll
        for (int off = 32; off > 0; off >>= 1) x += __shfl_xor(x, off, 64);
        if (lane == 0) red[0][wv] = x;   // visible after iter-0 barrier
    }

    float xi_eff = 0.0f;   // init f carries no pending shift; XI afterwards

    #pragma unroll 2
    for (int it = 0; it < NITER_; ++it) {
        const int p = it & 1;

        // ---- g partials: wave sums its own 64 rows (u via intra-wave shfl) ----
        float ax = 0.f, ay = 0.f, az = 0.f, aw = 0.f;
        #pragma unroll
        for (int j = 0; j < 16; ++j) {
            int row = w0 + 4 * j + r;
            float uw = __shfl(u_own, 4 * j + r, 64);
            uint2 raw = *reinterpret_cast<const uint2*>(&Es[row * LPH + 4 * cg]);
            float2 a = __half22float2(*reinterpret_cast<__half2*>(&raw.x));
            float2 b = __half22float2(*reinterpret_cast<__half2*>(&raw.y));
            ax = fmaf(uw, a.x, ax); ay = fmaf(uw, a.y, ay);
            az = fmaf(uw, b.x, az); aw = fmaf(uw, b.y, aw);
        }
        ax += __shfl_xor(ax, 16, 64); ay += __shfl_xor(ay, 16, 64);
        az += __shfl_xor(az, 16, 64); aw += __shfl_xor(aw, 16, 64);
        ax += __shfl_xor(ax, 32, 64); ay += __shfl_xor(ay, 32, 64);
        az += __shfl_xor(az, 32, 64); aw += __shfl_xor(aw, 32, 64);
        if (lane < 16)
            *reinterpret_cast<float4*>(&ps[p][w0 + 4 * cg]) =
                make_float4(ax, ay, az, aw);

        __syncthreads();   // THE barrier: ps[p] + red[p] from all waves visible

        // ---- scalar finish (all waves redundantly; everything wave-local) ----
        float R = ((red[p][0] + red[p][1]) + (red[p][2] + red[p][3]))
                + ((red[p][4] + red[p][5]) + (red[p][6] + red[p][7]));
        float sminF2 = -RHO * (log_a + __logf(R));
        float shift  = xi_eff * sminF2;       // pending XI*sminF2 from prev iter
        float sminF  = shift + sminF2;        // smin of actual f
        float S = 0.f;
        #pragma unroll
        for (int k = 0; k < 8; ++k) S += ps[p][k * 64 + lane];
        float appg = __logf(S) + shift;
        float ng2  = TAU * (log_b - appg) - KAPPA * sminF;
        float t = __expf(-ng2 * INV_RHO);
        #pragma unroll
        for (int off = 32; off > 0; off >>= 1) t += __shfl_xor(t, off, 64);
        float sminG2 = -RHO * (log_b + __logf(t));
        vsb[w0 + lane] = __expf(ng2 + XI * sminG2);  // own-wave slot, RAW in-wave
        float sminG = (1.0f + XI) * sminG2;

        // ---- f-phase: appf = log sum_c v[c]*ER[c] (LDS broadcast + registers) ----
        float s0 = 0.f, s1 = 0.f, s2 = 0.f, s3 = 0.f;
        #pragma unroll
        for (int k = 0; k < 16; ++k) {
            float4 v4 = *reinterpret_cast<const float4*>(&vsb[w0 + 4 * k]);
            s0 = fmaf(v4.x, ER[k].x, s0); s1 = fmaf(v4.y, ER[k].y, s1);
            s2 = fmaf(v4.z, ER[k].z, s2); s3 = fmaf(v4.w, ER[k].w, s3);
        }
        float appf = __logf((s0 + s1) + (s2 + s3));
        float nf2  = TAU * (log_a - appf) - KAPPA * sminG;
        u_own = __expf(nf2);                  // unnormalized: shift deferred
        float x = __expf(-nf2 * INV_RHO);
        #pragma unroll
        for (int off = 32; off > 0; off >>= 1) x += __shfl_xor(x, off, 64);
        if (lane == 0) red[p ^ 1][wv] = x;    // for next iter / final fixup
        xi_eff = XI;
    }

    // ---- final: apply last pending shift, share u via LDS, write output ----
    __syncthreads();   // red[0] (NITER even) from all waves visible
    {
        float R = ((red[0][0] + red[0][1]) + (red[0][2] + red[0][3]))
                + ((red[0][4] + red[0][5]) + (red[0][6] + red[0][7]));
        float sminF2 = -RHO * (log_a + __logf(R));
        ps[1][tid] = u_own * __expf(XI * sminF2);   // ps[1] dead, reuse as us
    }
    __syncthreads();

    #pragma unroll
    for (int i = 0; i < 16; ++i) {
        int fi = i * 512 + tid;
        int w  = fi >> 4;
        int c0 = (fi & 15) << 2;
        float uw = ps[1][w];
        float4 vv = *reinterpret_cast<const float4*>(&vsb[w0 + c0]);
        uint2 raw = *reinterpret_cast<const uint2*>(&Es[w * LPH + c0]);
        float2 a = __half22float2(*reinterpret_cast<__half2*>(&raw.x));
        float2 b = __half22float2(*reinterpret_cast<__half2*>(&raw.y));
        float4 o;
        o.x = uw * vv.x * a.x; o.y = uw * vv.y * a.y;
        o.z = uw * vv.z * b.x; o.w = uw * vv.w * b.y;
        outg4[fi] = o;
    }
}

extern "C" void kernel_launch(void* const* d_in, const int* in_sizes, int n_in,
                              void* d_out, int out_size, void* d_ws, size_t ws_size,
                              hipStream_t stream) {
    const float* C = (const float*)d_in[0];
    float* out = (float*)d_out;
    uot_sinkhorn_kernel<<<dim3(512), dim3(512), 0, stream>>>(C, out);
}

// Round 4
// 127.849 us; speedup vs baseline: 1.2078x; 1.2078x over previous
//
#include <hip/hip_runtime.h>

// UnbalancedOT Sinkhorn, B=4 H=128 W=512 C=64, EPS=1, TAU=0.95, 10 iters.
// E^T = exp(-C)^T stored fp16 in LDS [64][516] (66 KiB, 2 blocks/CU).
// Both matvecs via v_dot2_f32_f16 on packed fp16 (u, v carried as fp16;
// log-noise ~1e-3 -> output abs err ~6e-6, threshold 3.9e-5).
// g-phase: lane = column, contiguous-in-w reads, u as broadcast h4 loads
//   -> zero bpermutes in the inner loop.
// sminF block-reduce deferred: raw xs[] written pre-barrier-B, combined in
//   the NEXT g-phase (hidden under fdot2s). sminG2 wave-reduce overlaps the
//   f-loop via v~-factoring (v~=exp(ng2), appf corrected by +XI*sminG2).
// 2 barriers/iter; all LDS buffers single-buffered (A/B pair separates
// writers from readers -- checked per phase).

typedef _Float16 h2 __attribute__((ext_vector_type(2)));
typedef _Float16 h4 __attribute__((ext_vector_type(4)));

#define WD_ 512
#define CC_ 64
#define NITER_ 10
#define ETS 516   // E^T row stride in halves: 1032 B (8B-aligned rows, word
                  // bank=(2c+2j)%32 -> uniform 4/bank = b64 pipeline floor

__device__ __forceinline__ float fdot2(h2 a, h2 b, float c) {
    return __builtin_amdgcn_fdot2(a, b, c, false);
}

__global__ __launch_bounds__(512, 4)
void uot_sinkhorn_kernel(const float* __restrict__ C, float* __restrict__ out) {
    constexpr float TAU   = 0.95f;
    constexpr float KAPPA = 0.025f;           // (1-TAU)/2
    constexpr float XI    = 0.05f / 1.95f;    // (1-TAU)/(1+TAU)
    constexpr float RHO   = 19.0f;            // EPS*TAU/(1-TAU)
    constexpr float IR    = 1.0f / 19.0f;
    const float log_a = -6.2383246250395075f; // -log(512)
    const float log_b = -4.1588830833596715f; // -log(64)

    __shared__ __align__(16) _Float16 ET[CC_ * ETS];  // 66048 B: ET[c][w]
    __shared__ __align__(16) _Float16 us_h[WD_];      // u (unnormalized), fp16
    __shared__ __align__(16) _Float16 vsb[WD_];       // per-wave v~ slots [8][64]
    __shared__ __align__(16) float    ps[WD_];        // g col partials [8][64]
    __shared__ __align__(16) float    xs[WD_];        // exp(-nf2/rho) per row

    const int tid  = threadIdx.x;
    const int lane = tid & 63;
    const int wv   = tid >> 6;
    const int w0   = wv * 64;

    const size_t base = (size_t)blockIdx.x * (WD_ * CC_);
    const float4* Cg4   = reinterpret_cast<const float4*>(C + base);
    float4*       outg4 = reinterpret_cast<float4*>(out + base);

    // ---- stage: coalesced float4 loads of C, scatter E=exp(-C) into ET fp16 ----
    #pragma unroll
    for (int i = 0; i < 16; ++i) {
        int fi = i * 512 + tid;
        float4 v = Cg4[fi];
        int w  = fi >> 4;
        int c0 = (fi & 15) << 2;
        ET[(c0 + 0) * ETS + w] = (_Float16)__expf(-v.x);
        ET[(c0 + 1) * ETS + w] = (_Float16)__expf(-v.y);
        ET[(c0 + 2) * ETS + w] = (_Float16)__expf(-v.z);
        ET[(c0 + 3) * ETS + w] = (_Float16)__expf(-v.w);
    }
    __syncthreads();

    // ---- own-row packed register copy from rounded ET (exact consistency) ----
    h2 ER[32];
    #pragma unroll
    for (int k = 0; k < 32; ++k) {
        h2 e; e[0] = ET[(2 * k) * ETS + tid]; e[1] = ET[(2 * k + 1) * ETS + tid];
        ER[k] = e;
    }

    // ---- init f: fv = -(log_b + log sum_c E[row,:]) ----
    {
        const h2 ones = { (_Float16)1.0f, (_Float16)1.0f };
        float s0 = 0.f, s1 = 0.f, s2 = 0.f, s3 = 0.f;
        #pragma unroll
        for (int k = 0; k < 32; k += 4) {
            s0 = fdot2(ER[k + 0], ones, s0); s1 = fdot2(ER[k + 1], ones, s1);
            s2 = fdot2(ER[k + 2], ones, s2); s3 = fdot2(ER[k + 3], ones, s3);
        }
        float fv = -(log_b + __logf((s0 + s1) + (s2 + s3)));
        us_h[tid] = (_Float16)__expf(fv);     // true f (no pending shift)
        xs[tid]   = __expf(-fv * IR);
    }
    __syncthreads();   // B0: us_h, xs visible

    float xi_eff = 0.0f;       // pending-shift factor (0 for init f, XI after)
    float sminG2_last = 0.0f;

    for (int it = 0; it < NITER_; ++it) {
        // ---- g-phase: lane = column; sum own wave's 64 rows via fdot2 ----
        float a0 = 0.f, a1 = 0.f, a2 = 0.f, a3 = 0.f;
        #pragma unroll
        for (int j = 0; j < 16; j += 2) {
            h4 e0 = *reinterpret_cast<const h4*>(&ET[lane * ETS + w0 + 4 * j]);
            h4 u0 = *reinterpret_cast<const h4*>(&us_h[w0 + 4 * j]);
            h4 e1 = *reinterpret_cast<const h4*>(&ET[lane * ETS + w0 + 4 * j + 4]);
            h4 u1 = *reinterpret_cast<const h4*>(&us_h[w0 + 4 * j + 4]);
            h2 ea = {e0[0], e0[1]}, eb = {e0[2], e0[3]};
            h2 ua = {u0[0], u0[1]}, ub = {u0[2], u0[3]};
            h2 ec = {e1[0], e1[1]}, ed = {e1[2], e1[3]};
            h2 uc = {u1[0], u1[1]}, ud = {u1[2], u1[3]};
            a0 = fdot2(ea, ua, a0); a1 = fdot2(eb, ub, a1);
            a2 = fdot2(ec, uc, a2); a3 = fdot2(ed, ud, a3);
        }
        ps[tid] = (a0 + a1) + (a2 + a3);

        // overlapped: combine xs -> R (block sum of exp(-nf2/rho))
        float r = 0.f;
        #pragma unroll
        for (int k = 0; k < 8; ++k) r += xs[k * 64 + lane];
        #pragma unroll
        for (int off = 32; off > 0; off >>= 1) r += __shfl_xor(r, off, 64);

        __syncthreads();   // A: ps from all waves visible

        // ---- finish (lane = column, every wave computes its own v copy) ----
        float sminF2 = -RHO * (log_a + __logf(r));
        float shift  = xi_eff * sminF2;       // pending XI*sminF2 on u
        float sminF  = shift + sminF2;
        float S = 0.f;
        #pragma unroll
        for (int k = 0; k < 8; ++k) S += ps[k * 64 + lane];
        float appg = __logf(S) + shift;
        float ng2  = TAU * (log_b - appg) - KAPPA * sminF;
        vsb[tid] = (_Float16)__expf(ng2);     // v~ (no XI*sminG2 yet), own-wave slot
        float t = __expf(-ng2 * IR);          // sminG reduce, overlaps f-loop
        #pragma unroll
        for (int off = 32; off > 0; off >>= 1) t += __shfl_xor(t, off, 64);
        float sminG2 = -RHO * (log_b + __logf(t));

        // ---- f-phase: appf' = log sum_c v~[c] E[row,c] via fdot2 ----
        float s0 = 0.f, s1 = 0.f, s2 = 0.f, s3 = 0.f;
        #pragma unroll
        for (int q = 0; q < 16; q += 2) {
            h4 vb0 = *reinterpret_cast<const h4*>(&vsb[w0 + 4 * q]);
            h4 vb1 = *reinterpret_cast<const h4*>(&vsb[w0 + 4 * q + 4]);
            h2 va = {vb0[0], vb0[1]}, vbb = {vb0[2], vb0[3]};
            h2 vc = {vb1[0], vb1[1]}, vd  = {vb1[2], vb1[3]};
            s0 = fdot2(ER[2 * q + 0], va,  s0);
            s1 = fdot2(ER[2 * q + 1], vbb, s1);
            s2 = fdot2(ER[2 * q + 2], vc,  s2);
            s3 = fdot2(ER[2 * q + 3], vd,  s3);
        }
        float appf = __logf((s0 + s1) + (s2 + s3));   // missing +XI*sminG2
        float nf2  = TAU * (log_a - appf - XI * sminG2)
                   - KAPPA * (1.0f + XI) * sminG2;
        float u_own = __expf(nf2);            // unnormalized (shift deferred)
        us_h[tid] = (_Float16)u_own;
        xs[tid]   = __expf(-nf2 * IR);
        xi_eff = XI;
        sminG2_last = sminG2;
        __syncthreads();   // B: us_h, xs, vsb(last iter) visible
    }

    // ---- final fixup: last pending shifts folded into one scalar ----
    float r = 0.f;
    #pragma unroll
    for (int k = 0; k < 8; ++k) r += xs[k * 64 + lane];
    #pragma unroll
    for (int off = 32; off > 0; off >>= 1) r += __shfl_xor(r, off, 64);
    float sminF2 = -RHO * (log_a + __logf(r));
    const float SUV = __expf(XI * (sminF2 + sminG2_last));

    // ---- output: out = SUV * u[w] * v~[c] * E[w,c], coalesced float4 stores ----
    #pragma unroll
    for (int i = 0; i < 16; ++i) {
        int fi = i * 512 + tid;
        int w  = fi >> 4;
        int c0 = (fi & 15) << 2;
        float uf = SUV * (float)us_h[w];
        float4 o;
        o.x = uf * (float)vsb[w0 + c0 + 0] * (float)ET[(c0 + 0) * ETS + w];
        o.y = uf * (float)vsb[w0 + c0 + 1] * (float)ET[(c0 + 1) * ETS + w];
        o.z = uf * (float)vsb[w0 + c0 + 2] * (float)ET[(c0 + 2) * ETS + w];
        o.w = uf * (float)vsb[w0 + c0 + 3] * (float)ET[(c0 + 3) * ETS + w];
        outg4[fi] = o;
    }
}

extern "C" void kernel_launch(void* const* d_in, const int* in_sizes, int n_in,
                              void* d_out, int out_size, void* d_ws, size_t ws_size,
                              hipStream_t stream) {
    const float* C = (const float*)d_in[0];
    float* out = (float*)d_out;
    uot_sinkhorn_kernel<<<dim3(512), dim3(512), 0, stream>>>(C, out);
}